// Round 1
// baseline (785.585 us; speedup 1.0000x reference)
//
#include <hip/hip_runtime.h>

// LSTM RNN_20263655702953 — MI355X (gfx950)
//
// Reference quirk: hs[:, -1, :] selects BATCH index 511 across all T steps.
// => only batch element 511 matters. Single sequential LSTM chain:
//    1024 steps x (256x64 matvec + gates), record h_t, then (1024,64)@(64,2).
// Latency-bound: one workgroup of 256 threads (4 waves, 1 per SIMD of one CU).
//
// Mapping: wave g (tid>>6) owns gate g (i,f,g,o); lane l owns hidden unit l.
// W_hh row (64 floats) lives in VGPRs per lane. h broadcast is done with
// v_readlane (VALU->SGPR) instead of LDS reads: LDS broadcast of 64 floats to
// all 256 lanes would cost ~512 DS-cycles/step on the shared return bus;
// readlane+fma is 128 VALU instrs/wave/step, parallel across 4 SIMDs.
// c/h update computed redundantly by every wave (replicated h,c registers)
// => one barrier per step, gbuf double-buffered on t&1.
// h history: 64-step LDS ring flushed to d_ws (global stores drain overlapped
// with the next step's gate phase, not on every barrier).

#define T_LEN 1024
#define BATCH 512
#define HID   64

__device__ __forceinline__ float readlane_f(float v, int lane) {
    return __int_as_float(__builtin_amdgcn_readlane(__float_as_int(v), lane));
}
__device__ __forceinline__ float fast_rcp(float x) {
    return __builtin_amdgcn_rcpf(x);  // v_rcp_f32, ~1e-7 rel err
}
__device__ __forceinline__ float fast_sigmoid(float x) {
    return fast_rcp(1.0f + __expf(-x));
}
__device__ __forceinline__ float fast_tanh(float x) {
    // 1 - 2/(e^{2x}+1); saturates correctly for |x| large (exp->0 or inf)
    return 1.0f - 2.0f * fast_rcp(__expf(2.0f * x) + 1.0f);
}

__global__ __launch_bounds__(256, 1)
void lstm_seq_kernel(const float* __restrict__ x,
                     const float* __restrict__ W_ih,
                     const float* __restrict__ W_hh,
                     const float* __restrict__ b_ih,
                     const float* __restrict__ b_hh,
                     const float* __restrict__ W_fc,
                     const float* __restrict__ b_fc,
                     float* __restrict__ out,
                     float* __restrict__ hist)   // d_ws: 1024*64 floats
{
    __shared__ float xs[2 * T_LEN];      // 8 KB: x[:,511,:]
    __shared__ float gbuf[2 * 256];      // 2 KB: double-buffered activated gates
    __shared__ float hring[64 * HID];    // 16 KB: ring of last 64 h vectors

    const int tid  = threadIdx.x;
    const int lane = tid & 63;
    const int gate = tid >> 6;           // 0..3 = i,f,g,o ; == wave id
    const int row  = tid;                // gate row in [0,256)

    // ---- stage x[:,511,:] into LDS (scattered 8B loads, one-time ~64KB fetch)
    for (int j = 0; j < 4; ++j) {
        int t = tid + j * 256;           // 0..1023
        const float2 v = *(const float2*)(x + (size_t)(t * BATCH + (BATCH - 1)) * 2);
        xs[2 * t]     = v.x;
        xs[2 * t + 1] = v.y;
    }

    // ---- preload this lane's W_hh row into VGPRs (64 floats)
    float w[HID];
    {
        const float4* wr = (const float4*)(W_hh + row * HID);
        #pragma unroll
        for (int k = 0; k < HID / 4; ++k) {
            float4 v = wr[k];
            w[4*k+0] = v.x; w[4*k+1] = v.y; w[4*k+2] = v.z; w[4*k+3] = v.w;
        }
    }
    const float bsum = b_ih[row] + b_hh[row];
    const float wi0  = W_ih[row * 2 + 0];
    const float wi1  = W_ih[row * 2 + 1];

    float hval = 0.0f;   // lane l holds h[l]  (replicated in every wave)
    float cval = 0.0f;   // lane l holds c[l]  (replicated in every wave)

    __syncthreads();

    for (int t = 0; t < T_LEN; ++t) {
        // ---- gate phase: acc = b + W_ih@x_t + W_hh@h  (h via readlane bcast)
        float a0 = fmaf(wi0, xs[2 * t], bsum);
        float a1 = wi1 * xs[2 * t + 1];
        float a2 = 0.0f, a3 = 0.0f;
        #pragma unroll
        for (int k = 0; k < HID / 4; ++k) {
            a0 = fmaf(w[4*k+0], readlane_f(hval, 4*k+0), a0);
            a1 = fmaf(w[4*k+1], readlane_f(hval, 4*k+1), a1);
            a2 = fmaf(w[4*k+2], readlane_f(hval, 4*k+2), a2);
            a3 = fmaf(w[4*k+3], readlane_f(hval, 4*k+3), a3);
        }
        const float acc = (a0 + a1) + (a2 + a3);
        const float act = (gate == 2) ? fast_tanh(acc) : fast_sigmoid(acc);

        const int gb = (t & 1) * 256;
        gbuf[gb + row] = act;
        __syncthreads();   // the only per-step barrier

        // ---- update phase (redundant in all 4 waves; keeps h,c replicated)
        const float gi = gbuf[gb + lane];
        const float gf = gbuf[gb + 64 + lane];
        const float gg = gbuf[gb + 128 + lane];
        const float go = gbuf[gb + 192 + lane];
        cval = fmaf(gf, cval, gi * gg);
        hval = go * fast_tanh(cval);

        if (gate == 0) hring[(t & 63) * HID + lane] = hval;

        if ((t & 63) == 63) {            // uniform condition
            __syncthreads();             // make ring writes visible
            float4*       dst = (float4*)(hist + (t - 63) * HID);
            const float4* src = (const float4*)hring;
            #pragma unroll
            for (int j = 0; j < 4; ++j)  // 4096 floats, coalesced
                dst[tid * 4 + j] = src[tid * 4 + j];
            // stores drain at next step's barrier, overlapped with gate phase
        }
    }

    __syncthreads();  // drains final flush stores (vmcnt(0) before s_barrier)

    // ---- projection: out[t,o] = b_fc[o] + dot(W_fc[o,:], hist[t,:])
    #pragma unroll
    for (int j = 0; j < 8; ++j) {
        const int idx = tid + j * 256;   // 0..2047, coalesced stores
        const int t   = idx >> 1;
        const int o   = idx & 1;
        const float4* hv = (const float4*)(hist + t * HID);
        const float4* wv = (const float4*)(W_fc + o * HID);
        float p0 = 0.f, p1 = 0.f, p2 = 0.f, p3 = 0.f;
        #pragma unroll
        for (int k = 0; k < HID / 4; ++k) {
            float4 h4 = hv[k], w4 = wv[k];
            p0 = fmaf(h4.x, w4.x, p0);
            p1 = fmaf(h4.y, w4.y, p1);
            p2 = fmaf(h4.z, w4.z, p2);
            p3 = fmaf(h4.w, w4.w, p3);
        }
        out[idx] = b_fc[o] + ((p0 + p1) + (p2 + p3));
    }
}

extern "C" void kernel_launch(void* const* d_in, const int* in_sizes, int n_in,
                              void* d_out, int out_size, void* d_ws, size_t ws_size,
                              hipStream_t stream) {
    const float* x    = (const float*)d_in[0];
    const float* W_ih = (const float*)d_in[1];
    const float* W_hh = (const float*)d_in[2];
    const float* b_ih = (const float*)d_in[3];
    const float* b_hh = (const float*)d_in[4];
    const float* W_fc = (const float*)d_in[5];
    const float* b_fc = (const float*)d_in[6];
    float* out  = (float*)d_out;
    float* hist = (float*)d_ws;   // needs 1024*64*4 = 256 KB

    lstm_seq_kernel<<<dim3(1), dim3(256), 0, stream>>>(
        x, W_ih, W_hh, b_ih, b_hh, W_fc, b_fc, out, hist);
}

// Round 2
// 642.181 us; speedup vs baseline: 1.2233x; 1.2233x over previous
//
#include <hip/hip_runtime.h>

// LSTM RNN_20263655702953 — MI355X (gfx950), round 2.
//
// Reference quirk: hs[:, -1, :] selects BATCH index 511 across all T steps
// => single sequential LSTM chain (1024 steps, H=64), then (1024,64)@(64,2).
// One workgroup, 4 waves (1/SIMD); wave g owns gate g, lane l owns unit l.
//
// R1 change: broadcast of h via 16 rotated ds_read_b128 from a WAVE-PRIVATE
// double-buffered LDS copy (written by the wave itself after the update)
// instead of 64 v_readlane. Removes SGPR hazards/pressure; FMAs are pure
// VGPR. W_hh rows are pre-permuted at load so register indices stay
// compile-time: lane l, iter j uses chunk c=(j+(l&15))&15. 16 lane-groups
// hit 16 distinct 16B chunks => 2-way bank aliasing (free), groups merge as
// broadcast. Still exactly ONE barrier per step (gbuf gate exchange).

#define T_LEN 1024
#define BATCH 512
#define HID   64

__device__ __forceinline__ float fast_rcp(float x) {
    return __builtin_amdgcn_rcpf(x);  // v_rcp_f32, ~1e-7 rel err
}
__device__ __forceinline__ float fast_sigmoid(float x) {
    return fast_rcp(1.0f + __expf(-x));
}
__device__ __forceinline__ float fast_tanh(float x) {
    // 1 - 2/(e^{2x}+1); saturates correctly for |x| large
    return 1.0f - 2.0f * fast_rcp(__expf(2.0f * x) + 1.0f);
}

__global__ __launch_bounds__(256, 1)
void lstm_seq_kernel(const float* __restrict__ x,
                     const float* __restrict__ W_ih,
                     const float* __restrict__ W_hh,
                     const float* __restrict__ b_ih,
                     const float* __restrict__ b_hh,
                     const float* __restrict__ W_fc,
                     const float* __restrict__ b_fc,
                     float* __restrict__ out,
                     float* __restrict__ hist)   // d_ws: 1024*64 floats
{
    __shared__ float xs[2 * T_LEN];         // 8 KB: x[:,511,:]
    __shared__ float gbuf[2 * 256];         // 2 KB: double-buffered activated gates
    __shared__ float hbuf[4][2][HID];       // 2 KB: per-wave double-buffered h copy
    __shared__ float hring[64 * HID];       // 16 KB: ring of last 64 h vectors

    const int tid  = threadIdx.x;
    const int lane = tid & 63;
    const int gate = tid >> 6;              // 0..3 = i,f,g,o ; == wave id
    const int row  = tid;                   // gate row in [0,256)
    const int l16  = lane & 15;

    // ---- stage x[:,511,:] into LDS (one-time)
    for (int j = 0; j < 4; ++j) {
        int t = tid + j * 256;              // 0..1023
        const float2 v = *(const float2*)(x + (size_t)(t * BATCH + (BATCH - 1)) * 2);
        xs[2 * t]     = v.x;
        xs[2 * t + 1] = v.y;
    }

    // ---- preload this lane's W_hh row, PRE-PERMUTED for rotated broadcast:
    // iter j consumes h chunk c=(j+l16)&15, so w[4j..4j+3] = W_row[4c..4c+3].
    float w[HID];
    {
        const float* wr = W_hh + row * HID;
        #pragma unroll
        for (int j = 0; j < 16; ++j) {
            const int c = (j + l16) & 15;
            const float4 v = *(const float4*)(wr + 4 * c);
            w[4*j+0] = v.x; w[4*j+1] = v.y; w[4*j+2] = v.z; w[4*j+3] = v.w;
        }
    }
    const float bsum = b_ih[row] + b_hh[row];
    const float wi0  = W_ih[row * 2 + 0];
    const float wi1  = W_ih[row * 2 + 1];

    float hval = 0.0f;   // lane l holds h[l]  (replicated in every wave)
    float cval = 0.0f;   // lane l holds c[l]

    // init this wave's h buffer (t=0 reads buffer 0)
    hbuf[gate][0][lane] = 0.0f;

    __syncthreads();

    for (int t = 0; t < T_LEN; ++t) {
        // ---- gate phase: acc = b + W_ih@x_t + W_hh@h (rotated b128 broadcast)
        const float* hb = &hbuf[gate][t & 1][0];
        const float2 xv = *(const float2*)(xs + 2 * t);   // uniform-addr bcast
        float a0 = fmaf(wi0, xv.x, bsum);
        float a1 = wi1 * xv.y;
        float a2 = 0.0f, a3 = 0.0f;
        #pragma unroll
        for (int j = 0; j < 16; ++j) {
            const int c = (j + l16) & 15;
            const float4 hv = *(const float4*)(hb + 4 * c);
            a0 = fmaf(w[4*j+0], hv.x, a0);
            a1 = fmaf(w[4*j+1], hv.y, a1);
            a2 = fmaf(w[4*j+2], hv.z, a2);
            a3 = fmaf(w[4*j+3], hv.w, a3);
        }
        const float acc = (a0 + a1) + (a2 + a3);
        const float act = (gate == 2) ? fast_tanh(acc) : fast_sigmoid(acc);

        const int gb = (t & 1) * 256;
        gbuf[gb + row] = act;
        __syncthreads();   // the only per-step barrier

        // ---- update phase (redundant in all 4 waves; keeps h,c replicated)
        const float gi = gbuf[gb + lane];
        const float gf = gbuf[gb + 64 + lane];
        const float gg = gbuf[gb + 128 + lane];
        const float go = gbuf[gb + 192 + lane];
        cval = fmaf(gf, cval, gi * gg);
        hval = go * fast_tanh(cval);

        // wave-private h copy for next step's rotated broadcast (no barrier
        // needed: same-wave ds_write -> ds_read ordered by lgkmcnt)
        hbuf[gate][(t + 1) & 1][lane] = hval;

        if (gate == 0) hring[(t & 63) * HID + lane] = hval;

        if ((t & 63) == 63) {               // uniform condition
            __syncthreads();                // make ring writes visible
            float4*       dst = (float4*)(hist + (t - 63) * HID);
            const float4* src = (const float4*)hring;
            #pragma unroll
            for (int j = 0; j < 4; ++j)     // 4096 floats, coalesced
                dst[tid * 4 + j] = src[tid * 4 + j];
            // stores drain at next step's barrier, overlapped with gate phase
        }
    }

    __syncthreads();  // drains final flush stores

    // ---- projection: out[t,o] = b_fc[o] + dot(W_fc[o,:], hist[t,:])
    #pragma unroll
    for (int j = 0; j < 8; ++j) {
        const int idx = tid + j * 256;      // 0..2047, coalesced stores
        const int t   = idx >> 1;
        const int o   = idx & 1;
        const float4* hv = (const float4*)(hist + t * HID);
        const float4* wv = (const float4*)(W_fc + o * HID);
        float p0 = 0.f, p1 = 0.f, p2 = 0.f, p3 = 0.f;
        #pragma unroll
        for (int k = 0; k < HID / 4; ++k) {
            float4 h4 = hv[k], w4 = wv[k];
            p0 = fmaf(h4.x, w4.x, p0);
            p1 = fmaf(h4.y, w4.y, p1);
            p2 = fmaf(h4.z, w4.z, p2);
            p3 = fmaf(h4.w, w4.w, p3);
        }
        out[idx] = b_fc[o] + ((p0 + p1) + (p2 + p3));
    }
}

extern "C" void kernel_launch(void* const* d_in, const int* in_sizes, int n_in,
                              void* d_out, int out_size, void* d_ws, size_t ws_size,
                              hipStream_t stream) {
    const float* x    = (const float*)d_in[0];
    const float* W_ih = (const float*)d_in[1];
    const float* W_hh = (const float*)d_in[2];
    const float* b_ih = (const float*)d_in[3];
    const float* b_hh = (const float*)d_in[4];
    const float* W_fc = (const float*)d_in[5];
    const float* b_fc = (const float*)d_in[6];
    float* out  = (float*)d_out;
    float* hist = (float*)d_ws;   // needs 1024*64*4 = 256 KB

    lstm_seq_kernel<<<dim3(1), dim3(256), 0, stream>>>(
        x, W_ih, W_hh, b_ih, b_hh, W_fc, b_fc, out, hist);
}

// Round 3
// 553.703 us; speedup vs baseline: 1.4188x; 1.1598x over previous
//
#include <hip/hip_runtime.h>

// LSTM RNN_20263655702953 — MI355X (gfx950), round 3.
//
// Reference quirk: hs[:, -1, :] selects BATCH index 511 => single sequential
// LSTM chain (1024 steps, H=64), then (1024,64)@(64,2) projection.
// One workgroup, 4 waves (1/SIMD); wave g owns gate g, lane l owns unit l.
//
// R3 changes (fixing R2's serialized-LDS stall, VGPR=76 => no pipelining):
//  - h broadcast: 16 UNIFORM-address ds_read_b128 (broadcast reads are
//    conflict-free) batched into an explicit float4 hv[16] register array
//    (64 VGPRs) so all 16 reads are in flight before the FMA stream
//    consumes them with staged lgkmcnt waits. One vaddr + imm offsets:
//    zero per-read address math. W rows in natural order again.
//  - h-history ring written AND flushed by wave 0 only (its own data =>
//    no barrier); global stores drain off the critical path.
//  - still exactly ONE barrier per step (gbuf gate exchange).

#define T_LEN 1024
#define BATCH 512
#define HID   64

__device__ __forceinline__ float fast_rcp(float x) {
    return __builtin_amdgcn_rcpf(x);  // v_rcp_f32, ~1e-7 rel err
}
__device__ __forceinline__ float fast_sigmoid(float x) {
    return fast_rcp(1.0f + __expf(-x));
}
__device__ __forceinline__ float fast_tanh(float x) {
    // 1 - 2/(e^{2x}+1); saturates correctly for |x| large
    return 1.0f - 2.0f * fast_rcp(__expf(2.0f * x) + 1.0f);
}

__global__ __launch_bounds__(256, 1)
void lstm_seq_kernel(const float* __restrict__ x,
                     const float* __restrict__ W_ih,
                     const float* __restrict__ W_hh,
                     const float* __restrict__ b_ih,
                     const float* __restrict__ b_hh,
                     const float* __restrict__ W_fc,
                     const float* __restrict__ b_fc,
                     float* __restrict__ out,
                     float* __restrict__ hist)   // d_ws: 1024*64 floats
{
    __shared__ float xs[2 * T_LEN];         // 8 KB: x[:,511,:]
    __shared__ float gbuf[2 * 256];         // 2 KB: double-buffered activated gates
    __shared__ float hbuf[4][2][HID];       // 2 KB: per-wave double-buffered h copy
    __shared__ float hring[64 * HID];       // 16 KB: ring of last 64 h (wave 0 only)

    const int tid  = threadIdx.x;
    const int lane = tid & 63;
    const int gate = tid >> 6;              // 0..3 = i,f,g,o ; == wave id
    const int row  = tid;                   // gate row in [0,256)

    // ---- stage x[:,511,:] into LDS (one-time)
    for (int j = 0; j < 4; ++j) {
        int t = tid + j * 256;              // 0..1023
        const float2 v = *(const float2*)(x + (size_t)(t * BATCH + (BATCH - 1)) * 2);
        xs[2 * t]     = v.x;
        xs[2 * t + 1] = v.y;
    }

    // ---- preload this lane's W_hh row (natural order) into VGPRs
    float w[HID];
    {
        const float4* wr = (const float4*)(W_hh + row * HID);
        #pragma unroll
        for (int k = 0; k < HID / 4; ++k) {
            float4 v = wr[k];
            w[4*k+0] = v.x; w[4*k+1] = v.y; w[4*k+2] = v.z; w[4*k+3] = v.w;
        }
    }
    const float bsum = b_ih[row] + b_hh[row];
    const float wi0  = W_ih[row * 2 + 0];
    const float wi1  = W_ih[row * 2 + 1];

    float hval = 0.0f;   // lane l holds h[l]  (replicated in every wave)
    float cval = 0.0f;   // lane l holds c[l]

    // init this wave's h buffer (t=0 reads buffer 0); same-wave write->read
    hbuf[gate][0][lane] = 0.0f;

    __syncthreads();

    for (int t = 0; t < T_LEN; ++t) {
        // ---- gate phase: acc = b + W_ih@x_t + W_hh@h
        // 16 uniform-address (broadcast, conflict-free) ds_read_b128, all
        // issued before consumption => pipelined, staged lgkmcnt waits.
        const float4* hb = (const float4*)&hbuf[gate][t & 1][0];
        float4 hv[16];
        #pragma unroll
        for (int j = 0; j < 16; ++j) hv[j] = hb[j];

        const float2 xv = *(const float2*)(xs + 2 * t);   // uniform bcast
        float a0 = fmaf(wi0, xv.x, bsum);
        float a1 = wi1 * xv.y;
        float a2 = 0.0f, a3 = 0.0f;
        #pragma unroll
        for (int j = 0; j < 16; ++j) {
            a0 = fmaf(w[4*j+0], hv[j].x, a0);
            a1 = fmaf(w[4*j+1], hv[j].y, a1);
            a2 = fmaf(w[4*j+2], hv[j].z, a2);
            a3 = fmaf(w[4*j+3], hv[j].w, a3);
        }
        const float acc = (a0 + a1) + (a2 + a3);
        const float act = (gate == 2) ? fast_tanh(acc) : fast_sigmoid(acc);

        const int gb = (t & 1) * 256;
        gbuf[gb + row] = act;
        __syncthreads();   // the only per-step barrier

        // ---- update phase (redundant in all 4 waves; keeps h,c replicated)
        const float gi = gbuf[gb + lane];
        const float gf = gbuf[gb + 64 + lane];
        const float gg = gbuf[gb + 128 + lane];
        const float go = gbuf[gb + 192 + lane];
        cval = fmaf(gf, cval, gi * gg);
        hval = go * fast_tanh(cval);

        // wave-private h copy for next step's broadcast (same-wave order)
        hbuf[gate][(t + 1) & 1][lane] = hval;

        // h history: wave 0 owns the ring AND the flush (own data => no
        // barrier; stores drain off-path, absorbed by later barriers)
        if (gate == 0) {
            hring[(t & 63) * HID + lane] = hval;
            if ((t & 63) == 63) {
                float4*       dst = (float4*)(hist + (t - 63) * HID);
                const float4* src = (const float4*)hring;
                #pragma unroll
                for (int j = 0; j < 16; ++j)     // 4096 floats, coalesced
                    dst[lane + 64 * j] = src[lane + 64 * j];
            }
        }
    }

    __syncthreads();  // wave0's final flush drained & visible (block fence)

    // ---- projection: out[t,o] = b_fc[o] + dot(W_fc[o,:], hist[t,:])
    #pragma unroll
    for (int j = 0; j < 8; ++j) {
        const int idx = tid + j * 256;      // 0..2047, coalesced stores
        const int t   = idx >> 1;
        const int o   = idx & 1;
        const float4* hv4 = (const float4*)(hist + t * HID);
        const float4* wv  = (const float4*)(W_fc + o * HID);
        float p0 = 0.f, p1 = 0.f, p2 = 0.f, p3 = 0.f;
        #pragma unroll
        for (int k = 0; k < HID / 4; ++k) {
            float4 h4 = hv4[k], w4 = wv[k];
            p0 = fmaf(h4.x, w4.x, p0);
            p1 = fmaf(h4.y, w4.y, p1);
            p2 = fmaf(h4.z, w4.z, p2);
            p3 = fmaf(h4.w, w4.w, p3);
        }
        out[idx] = b_fc[o] + ((p0 + p1) + (p2 + p3));
    }
}

extern "C" void kernel_launch(void* const* d_in, const int* in_sizes, int n_in,
                              void* d_out, int out_size, void* d_ws, size_t ws_size,
                              hipStream_t stream) {
    const float* x    = (const float*)d_in[0];
    const float* W_ih = (const float*)d_in[1];
    const float* W_hh = (const float*)d_in[2];
    const float* b_ih = (const float*)d_in[3];
    const float* b_hh = (const float*)d_in[4];
    const float* W_fc = (const float*)d_in[5];
    const float* b_fc = (const float*)d_in[6];
    float* out  = (float*)d_out;
    float* hist = (float*)d_ws;   // needs 1024*64*4 = 256 KB

    lstm_seq_kernel<<<dim3(1), dim3(256), 0, stream>>>(
        x, W_ih, W_hh, b_ih, b_hh, W_fc, b_fc, out, hist);
}

// Round 4
// 484.110 us; speedup vs baseline: 1.6227x; 1.1438x over previous
//
#include <hip/hip_runtime.h>

// LSTM RNN_20263655702953 — MI355X (gfx950), round 4.
//
// Reference quirk: hs[:, -1, :] selects BATCH index 511 => single sequential
// LSTM chain (1024 steps, H=64), then (1024,64)@(64,2) projection.
// One workgroup, 4 waves (1/SIMD); wave g owns gate g, lane l owns unit l.
//
// R4 change: h broadcast via BATCHED v_readlane -> SGPR, consumed by
// v_fma_f32 with SGPR operand. No LDS on the h path at all (R3's staged
// ds_read waits were ~850 cyc/step). sched_barrier(0) fences force the
// shape [RL x16 | FMA x16 + RL x16 | ...] so VALU->SGPR hazards are spaced
// >=16 instrs and the FMA stream is pure issue. R0 failed with readlane
// because it interleaved RL+FMA per element (hazard every pair).
// Activation unified: sigmoid/tanh share one exp+rcp chain via per-thread
// (A,B,C): act = A*rcp(1+exp(B*acc))+C  — avoids dual-path codegen since
// `gate` is not provably wave-uniform to the compiler.
// Still exactly ONE barrier per step (gbuf gate exchange, double-buffered).

#define T_LEN 1024
#define BATCH 512
#define HID   64

__device__ __forceinline__ float fast_rcp(float x) {
    return __builtin_amdgcn_rcpf(x);  // v_rcp_f32, ~1e-7 rel err
}
__device__ __forceinline__ float fast_tanh(float x) {
    // 1 - 2/(e^{2x}+1); saturates correctly for |x| large
    return 1.0f - 2.0f * fast_rcp(__expf(2.0f * x) + 1.0f);
}

__global__ __launch_bounds__(256, 1)
void lstm_seq_kernel(const float* __restrict__ x,
                     const float* __restrict__ W_ih,
                     const float* __restrict__ W_hh,
                     const float* __restrict__ b_ih,
                     const float* __restrict__ b_hh,
                     const float* __restrict__ W_fc,
                     const float* __restrict__ b_fc,
                     float* __restrict__ out,
                     float* __restrict__ hist)   // d_ws: 1024*64 floats
{
    __shared__ float xs[2 * T_LEN];         // 8 KB: x[:,511,:]
    __shared__ float gbuf[2][4][HID];       // 2 KB: double-buffered gates [buf][gate][unit]
    __shared__ float hring[64 * HID];       // 16 KB: ring of last 64 h (wave 0 only)

    const int tid  = threadIdx.x;
    const int lane = tid & 63;
    const int gate = tid >> 6;              // 0..3 = i,f,g,o ; == wave id
    const int row  = tid;                   // gate row in [0,256)

    // ---- stage x[:,511,:] into LDS (one-time)
    for (int j = 0; j < 4; ++j) {
        int t = tid + j * 256;              // 0..1023
        const float2 v = *(const float2*)(x + (size_t)(t * BATCH + (BATCH - 1)) * 2);
        xs[2 * t]     = v.x;
        xs[2 * t + 1] = v.y;
    }

    // ---- preload this lane's W_hh row (natural order) into VGPRs
    float w[HID];
    {
        const float4* wr = (const float4*)(W_hh + row * HID);
        #pragma unroll
        for (int k = 0; k < HID / 4; ++k) {
            float4 v = wr[k];
            w[4*k+0] = v.x; w[4*k+1] = v.y; w[4*k+2] = v.z; w[4*k+3] = v.w;
        }
    }
    const float bsum = b_ih[row] + b_hh[row];
    const float wi0  = W_ih[row * 2 + 0];
    const float wi1  = W_ih[row * 2 + 1];

    // unified activation constants: sigmoid: 1*rcp(1+e^-x)+0 ; tanh: 2*rcp(1+e^-2x)-1
    const float actA = (gate == 2) ? 2.0f : 1.0f;
    const float actB = (gate == 2) ? -2.0f : -1.0f;
    const float actC = (gate == 2) ? -1.0f : 0.0f;

    float hval = 0.0f;   // lane l holds h[l]  (replicated in every wave)
    float cval = 0.0f;   // lane l holds c[l]

    __syncthreads();

    for (int t = 0; t < T_LEN; ++t) {
        // x-part load issued early (independent), consumed after FMA stream
        const float2 xv = *(const float2*)(xs + 2 * t);   // uniform bcast
        const int hb = __float_as_int(hval);

        float a0 = bsum, a1 = 0.0f, a2 = 0.0f, a3 = 0.0f;
        int hsA[16], hsB[16];

        // ---- RL batch 0
        #pragma unroll
        for (int k = 0; k < 16; ++k) hsA[k] = __builtin_amdgcn_readlane(hb, k);
        __builtin_amdgcn_sched_barrier(0);
        // ---- FMA batch 0 + RL batch 1
        #pragma unroll
        for (int k = 0; k < 16; k += 4) {
            a0 = fmaf(w[k+0], __int_as_float(hsA[k+0]), a0);
            a1 = fmaf(w[k+1], __int_as_float(hsA[k+1]), a1);
            a2 = fmaf(w[k+2], __int_as_float(hsA[k+2]), a2);
            a3 = fmaf(w[k+3], __int_as_float(hsA[k+3]), a3);
        }
        #pragma unroll
        for (int k = 0; k < 16; ++k) hsB[k] = __builtin_amdgcn_readlane(hb, 16 + k);
        __builtin_amdgcn_sched_barrier(0);
        // ---- FMA batch 1 + RL batch 2
        #pragma unroll
        for (int k = 0; k < 16; k += 4) {
            a0 = fmaf(w[16+k+0], __int_as_float(hsB[k+0]), a0);
            a1 = fmaf(w[16+k+1], __int_as_float(hsB[k+1]), a1);
            a2 = fmaf(w[16+k+2], __int_as_float(hsB[k+2]), a2);
            a3 = fmaf(w[16+k+3], __int_as_float(hsB[k+3]), a3);
        }
        #pragma unroll
        for (int k = 0; k < 16; ++k) hsA[k] = __builtin_amdgcn_readlane(hb, 32 + k);
        __builtin_amdgcn_sched_barrier(0);
        // ---- FMA batch 2 + RL batch 3
        #pragma unroll
        for (int k = 0; k < 16; k += 4) {
            a0 = fmaf(w[32+k+0], __int_as_float(hsA[k+0]), a0);
            a1 = fmaf(w[32+k+1], __int_as_float(hsA[k+1]), a1);
            a2 = fmaf(w[32+k+2], __int_as_float(hsA[k+2]), a2);
            a3 = fmaf(w[32+k+3], __int_as_float(hsA[k+3]), a3);
        }
        #pragma unroll
        for (int k = 0; k < 16; ++k) hsB[k] = __builtin_amdgcn_readlane(hb, 48 + k);
        __builtin_amdgcn_sched_barrier(0);
        // ---- FMA batch 3
        #pragma unroll
        for (int k = 0; k < 16; k += 4) {
            a0 = fmaf(w[48+k+0], __int_as_float(hsB[k+0]), a0);
            a1 = fmaf(w[48+k+1], __int_as_float(hsB[k+1]), a1);
            a2 = fmaf(w[48+k+2], __int_as_float(hsB[k+2]), a2);
            a3 = fmaf(w[48+k+3], __int_as_float(hsB[k+3]), a3);
        }

        // x contribution last (its LDS wait lands here, long since done)
        float acc = ((a0 + a1) + (a2 + a3));
        acc = fmaf(wi0, xv.x, acc);
        acc = fmaf(wi1, xv.y, acc);

        // unified activation: one exp + one rcp chain
        const float act = fmaf(actA, fast_rcp(1.0f + __expf(actB * acc)), actC);

        const int buf = t & 1;
        gbuf[buf][gate][lane] = act;        // conflict-free (contiguous per wave)
        __syncthreads();                    // the only per-step barrier

        // ---- update phase (redundant in all 4 waves; keeps h,c replicated)
        // 2x ds_read2_b32, conflict-free (2-way lane aliasing = free)
        const float gi = gbuf[buf][0][lane];
        const float gf = gbuf[buf][1][lane];
        const float gg = gbuf[buf][2][lane];
        const float go = gbuf[buf][3][lane];
        cval = fmaf(gf, cval, gi * gg);
        hval = go * fast_tanh(cval);

        // h history: wave 0 owns ring + flush (own data => no barrier;
        // global stores drain off the critical path)
        if (gate == 0) {
            hring[(t & 63) * HID + lane] = hval;
            if ((t & 63) == 63) {
                float4*       dst = (float4*)(hist + (t - 63) * HID);
                const float4* src = (const float4*)hring;
                #pragma unroll
                for (int j = 0; j < 16; ++j)     // 4096 floats, coalesced
                    dst[lane + 64 * j] = src[lane + 64 * j];
            }
        }
    }

    __syncthreads();  // wave0's final flush drained & visible (block fence)

    // ---- projection: out[t,o] = b_fc[o] + dot(W_fc[o,:], hist[t,:])
    #pragma unroll
    for (int j = 0; j < 8; ++j) {
        const int idx = tid + j * 256;      // 0..2047, coalesced stores
        const int t   = idx >> 1;
        const int o   = idx & 1;
        const float4* hv4 = (const float4*)(hist + t * HID);
        const float4* wv  = (const float4*)(W_fc + o * HID);
        float p0 = 0.f, p1 = 0.f, p2 = 0.f, p3 = 0.f;
        #pragma unroll
        for (int k = 0; k < HID / 4; ++k) {
            float4 h4 = hv4[k], w4 = wv[k];
            p0 = fmaf(h4.x, w4.x, p0);
            p1 = fmaf(h4.y, w4.y, p1);
            p2 = fmaf(h4.z, w4.z, p2);
            p3 = fmaf(h4.w, w4.w, p3);
        }
        out[idx] = b_fc[o] + ((p0 + p1) + (p2 + p3));
    }
}

extern "C" void kernel_launch(void* const* d_in, const int* in_sizes, int n_in,
                              void* d_out, int out_size, void* d_ws, size_t ws_size,
                              hipStream_t stream) {
    const float* x    = (const float*)d_in[0];
    const float* W_ih = (const float*)d_in[1];
    const float* W_hh = (const float*)d_in[2];
    const float* b_ih = (const float*)d_in[3];
    const float* b_hh = (const float*)d_in[4];
    const float* W_fc = (const float*)d_in[5];
    const float* b_fc = (const float*)d_in[6];
    float* out  = (float*)d_out;
    float* hist = (float*)d_ws;   // needs 1024*64*4 = 256 KB

    lstm_seq_kernel<<<dim3(1), dim3(256), 0, stream>>>(
        x, W_ih, W_hh, b_ih, b_hh, W_fc, b_fc, out, hist);
}